// Round 2
// baseline (60.027 us; speedup 1.0000x reference)
//
#include <hip/hip_runtime.h>

#define B_SZ   256
#define T_SZ   512
#define EMB    128
#define HID    256
#define NCLS   32000

typedef __attribute__((ext_vector_type(8))) short short8;
typedef __attribute__((ext_vector_type(4))) float f32x4;

__device__ inline unsigned short bf16rne(float f) {
    union { float f; unsigned int u; } v; v.f = f;
    unsigned int u = v.u;
    u += 0x7FFFu + ((u >> 16) & 1u);   // round-to-nearest-even
    return (unsigned short)(u >> 16);
}

// ---------------------------------------------------------------------------
// Kernel 1: h_last[b][k] = o0 * tanh(i0 * g0) for the LAST timestep only.
// (layer-0 state never updates; layer-1 scan is discarded; only t = T-1 used)
// 64 blocks x 256 threads; each block handles 4 batch rows, thread = one k.
// Output: bf16 row-major [256][256] into d_ws.
// ---------------------------------------------------------------------------
__global__ __launch_bounds__(256)
void lstm_h_last(const int* __restrict__ X, const float* __restrict__ C_table,
                 const float* __restrict__ U_i, const float* __restrict__ b_i,
                 const float* __restrict__ U_c, const float* __restrict__ b_c,
                 const float* __restrict__ U_o, const float* __restrict__ b_o,
                 unsigned short* __restrict__ hws) {
    __shared__ float e[4][EMB];
    __shared__ int idx[4];
    const int t  = threadIdx.x;          // 0..255
    const int b4 = blockIdx.x * 4;

    if (t < 4) idx[t] = X[(size_t)(b4 + t) * T_SZ + (T_SZ - 1)];
    __syncthreads();

    #pragma unroll
    for (int p = 0; p < 2; ++p) {
        int lin  = p * 256 + t;
        int r    = lin >> 7;
        int ei   = lin & 127;
        e[r][ei] = C_table[(size_t)idx[r] * EMB + ei];
    }
    __syncthreads();

    const int k = t;  // hidden index
    float ai[4] = {0.f, 0.f, 0.f, 0.f};
    float ac[4] = {0.f, 0.f, 0.f, 0.f};
    float ao[4] = {0.f, 0.f, 0.f, 0.f};

    for (int ee = 0; ee < EMB; ++ee) {
        float ui = U_i[ee * HID + k];
        float uc = U_c[ee * HID + k];
        float uo = U_o[ee * HID + k];
        #pragma unroll
        for (int r = 0; r < 4; ++r) {
            float ev = e[r][ee];
            ai[r] += ev * ui;
            ac[r] += ev * uc;
            ao[r] += ev * uo;
        }
    }

    const float bi = b_i[k], bc = b_c[k], bo = b_o[k];
    #pragma unroll
    for (int r = 0; r < 4; ++r) {
        float i0 = 1.f / (1.f + expf(-(ai[r] + bi)));
        float g0 = tanhf(ac[r] + bc);
        float o0 = 1.f / (1.f + expf(-(ao[r] + bo)));
        float c0 = i0 * g0;
        float h  = o0 * tanhf(c0);
        hws[(size_t)(b4 + r) * HID + k] = bf16rne(h);
    }
}

// ---------------------------------------------------------------------------
// Kernel 2: logits[m][n] = sum_k h[m][k] * W_w[n][k] + b_out[n]
// M=256 N=32000 K=256.  Pure streaming, NO LDS, NO barrier.
// Grid = 500 blocks x 256 threads (4 waves). Wave owns n-stripe of 16 rows
// (block covers 64 n), computes [16 n x 256 m].
// Operands SWAPPED vs naive: A = W rows, B = h rows, so D[n][m] has
// col=lane&15 = m, row = lq*4+reg = n -> 4 consecutive n per lane ->
// float4 output stores. W read from HBM exactly once (no wave redundancy);
// h (128 KB, L1/L2-resident) is the only redundant read.
// All 16 W float4 loads issued up front per wave -> max outstanding HBM.
// ---------------------------------------------------------------------------
__global__ __launch_bounds__(256, 2)
void logits_gemm(const unsigned short* __restrict__ hws,
                 const float* __restrict__ Ww,
                 const float* __restrict__ b_out,
                 float* __restrict__ out) {
    const int t    = threadIdx.x;        // 0..255
    const int wid  = t >> 6;             // 0..3
    const int lane = t & 63;
    const int l15  = lane & 15;
    const int lq   = lane >> 4;          // 0..3

    const int n_base = blockIdx.x * 64 + wid * 16;
    const int nrow   = n_base + l15;     // W row this lane loads (a-frag)

    // ---- preload the full K=256 stripe of W for this lane (16 float4) ----
    const float* wp = Ww + (size_t)nrow * HID + lq * 8;
    float4 wf[16];
    #pragma unroll
    for (int ks = 0; ks < 8; ++ks) {
        wf[2 * ks]     = *reinterpret_cast<const float4*>(wp + ks * 32);
        wf[2 * ks + 1] = *reinterpret_cast<const float4*>(wp + ks * 32 + 4);
    }

    // ---- convert to bf16 a-fragments (8 x short8) ----
    short8 aw[8];
    #pragma unroll
    for (int ks = 0; ks < 8; ++ks) {
        union { short8 s; unsigned int u[4]; } r;
        const float* f0 = reinterpret_cast<const float*>(&wf[2 * ks]);
        const float* f1 = reinterpret_cast<const float*>(&wf[2 * ks + 1]);
        r.u[0] = ((unsigned)bf16rne(f0[1]) << 16) | bf16rne(f0[0]);
        r.u[1] = ((unsigned)bf16rne(f0[3]) << 16) | bf16rne(f0[2]);
        r.u[2] = ((unsigned)bf16rne(f1[1]) << 16) | bf16rne(f1[0]);
        r.u[3] = ((unsigned)bf16rne(f1[3]) << 16) | bf16rne(f1[2]);
        aw[ks] = r.s;
    }

    // ---- K-loop: fully unrolled, 128 MFMA, b-frags straight from global ----
    const unsigned short* hb = hws + (size_t)l15 * HID + lq * 8;
    f32x4 acc[16] = {};
    #pragma unroll
    for (int ks = 0; ks < 8; ++ks) {
        #pragma unroll
        for (int mf = 0; mf < 16; ++mf) {
            short8 b = *reinterpret_cast<const short8*>(
                hb + (size_t)mf * 16 * HID + ks * 32);
            acc[mf] = __builtin_amdgcn_mfma_f32_16x16x32_bf16(
                aw[ks], b, acc[mf], 0, 0, 0);
        }
    }

    // ---- epilogue: lane holds 4 consecutive n for m = mf*16 + l15 ----
    float4 bias = *reinterpret_cast<const float4*>(b_out + n_base + lq * 4);
    f32x4 bv; bv[0] = bias.x; bv[1] = bias.y; bv[2] = bias.z; bv[3] = bias.w;
    #pragma unroll
    for (int mf = 0; mf < 16; ++mf) {
        f32x4 o = acc[mf] + bv;
        *reinterpret_cast<f32x4*>(
            out + (size_t)(mf * 16 + l15) * NCLS + n_base + lq * 4) = o;
    }
}

// ---------------------------------------------------------------------------
extern "C" void kernel_launch(void* const* d_in, const int* in_sizes, int n_in,
                              void* d_out, int out_size, void* d_ws, size_t ws_size,
                              hipStream_t stream) {
    const int*   X       = (const int*)  d_in[0];
    const float* C_table = (const float*)d_in[1];
    const float* U_i     = (const float*)d_in[2];
    const float* b_i     = (const float*)d_in[4];
    const float* U_c     = (const float*)d_in[8];
    const float* b_c     = (const float*)d_in[10];
    const float* U_o     = (const float*)d_in[11];
    const float* b_o     = (const float*)d_in[13];
    const float* W_w     = (const float*)d_in[26];
    const float* b_out   = (const float*)d_in[27];
    float* out = (float*)d_out;

    unsigned short* hws = (unsigned short*)d_ws;  // bf16 h_last [256][256]

    lstm_h_last<<<B_SZ / 4, 256, 0, stream>>>(X, C_table, U_i, b_i, U_c, b_c,
                                              U_o, b_o, hws);
    logits_gemm<<<NCLS / 64, 256, 0, stream>>>(hws, W_w, b_out, out);
}

// Round 3
// 44.274 us; speedup vs baseline: 1.3558x; 1.3558x over previous
//
#include <hip/hip_runtime.h>

#define B_SZ   256
#define T_SZ   512
#define EMB    128
#define HID    256
#define NCLS   32000

typedef __attribute__((ext_vector_type(8))) short short8;
typedef __attribute__((ext_vector_type(4))) float f32x4;

__device__ inline unsigned short bf16rne(float f) {
    union { float f; unsigned int u; } v; v.f = f;
    unsigned int u = v.u;
    u += 0x7FFFu + ((u >> 16) & 1u);   // round-to-nearest-even
    return (unsigned short)(u >> 16);
}

// ---------------------------------------------------------------------------
// Kernel 1: h_last[b][k] = o0 * tanh(i0 * g0) for the LAST timestep only.
// (layer-0 state never updates; layer-1 scan is discarded; only t = T-1 used)
// ---------------------------------------------------------------------------
__global__ __launch_bounds__(256)
void lstm_h_last(const int* __restrict__ X, const float* __restrict__ C_table,
                 const float* __restrict__ U_i, const float* __restrict__ b_i,
                 const float* __restrict__ U_c, const float* __restrict__ b_c,
                 const float* __restrict__ U_o, const float* __restrict__ b_o,
                 unsigned short* __restrict__ hws) {
    __shared__ float e[4][EMB];
    __shared__ int idx[4];
    const int t  = threadIdx.x;          // 0..255
    const int b4 = blockIdx.x * 4;

    if (t < 4) idx[t] = X[(size_t)(b4 + t) * T_SZ + (T_SZ - 1)];
    __syncthreads();

    #pragma unroll
    for (int p = 0; p < 2; ++p) {
        int lin  = p * 256 + t;
        int r    = lin >> 7;
        int ei   = lin & 127;
        e[r][ei] = C_table[(size_t)idx[r] * EMB + ei];
    }
    __syncthreads();

    const int k = t;  // hidden index
    float ai[4] = {0.f, 0.f, 0.f, 0.f};
    float ac[4] = {0.f, 0.f, 0.f, 0.f};
    float ao[4] = {0.f, 0.f, 0.f, 0.f};

    for (int ee = 0; ee < EMB; ++ee) {
        float ui = U_i[ee * HID + k];
        float uc = U_c[ee * HID + k];
        float uo = U_o[ee * HID + k];
        #pragma unroll
        for (int r = 0; r < 4; ++r) {
            float ev = e[r][ee];
            ai[r] += ev * ui;
            ac[r] += ev * uc;
            ao[r] += ev * uo;
        }
    }

    const float bi = b_i[k], bc = b_c[k], bo = b_o[k];
    #pragma unroll
    for (int r = 0; r < 4; ++r) {
        float i0 = 1.f / (1.f + expf(-(ai[r] + bi)));
        float g0 = tanhf(ac[r] + bc);
        float o0 = 1.f / (1.f + expf(-(ao[r] + bo)));
        float c0 = i0 * g0;
        float h  = o0 * tanhf(c0);
        hws[(size_t)(b4 + r) * HID + k] = bf16rne(h);
    }
}

// ---------------------------------------------------------------------------
// Kernel 2: logits[m][n] = sum_k h[m][k] * W_w[n][k] + b_out[n]
// M=256 N=32000 K=256.
//
// Inversion of round-2 design: h lives in REGISTERS (wave owns 32 m-rows,
// b-frags = 16 x short8 = 64 VGPR, read once from L2), streamed W goes
// through LDS (padded 264-bf16 rows, 0 bank conflicts measured in round 1).
//
// Grid = 2000 blocks x 256 thr (4 waves): bid&1 = m-group (0/1 -> m 0..127 /
// 128..255, fast-varying so both groups hit the same W lines in L3 near-
// concurrently), bid>>1 = n-tile of BN=32. Per block: 16 b-frag loads/lane +
// 8 coalesced float4 W loads/thread issued up front (high MLP), cvt->LDS,
// ONE barrier, 32 MFMA/wave from LDS, float4 stores. No inner-loop global
// latency chains; 3-4 resident blocks/CU overlap staging with compute.
// ---------------------------------------------------------------------------
#define BN      32
#define LDSROW  264   // bf16 elements per padded row (528 B)

__global__ __launch_bounds__(256)
void logits_gemm(const unsigned short* __restrict__ hws,
                 const float* __restrict__ Ww,
                 const float* __restrict__ b_out,
                 float* __restrict__ out) {
    __shared__ unsigned short Bs[BN * LDSROW];   // 16.9 KB

    const int t    = threadIdx.x;        // 0..255
    const int wid  = t >> 6;             // 0..3
    const int lane = t & 63;
    const int l15  = lane & 15;
    const int lq   = lane >> 4;          // 0..3

    const int bid  = blockIdx.x;
    const int mgrp = bid & 1;                    // m-group fast-varying
    const int nb   = (bid >> 1) * BN;            // n base (1000 tiles)
    const int m0   = mgrp * 128 + wid * 32;      // this wave's 32-m strip

    // ---- b-frags: h[m0 + mf*16 + l15][lq*8 + ks*32], kept in regs ----
    short8 bh[16];
    #pragma unroll
    for (int mf = 0; mf < 2; ++mf)
        #pragma unroll
        for (int ks = 0; ks < 8; ++ks)
            bh[mf * 8 + ks] = *reinterpret_cast<const short8*>(
                hws + (size_t)(m0 + mf * 16 + l15) * HID + lq * 8 + ks * 32);

    // ---- stage W[nb .. nb+31][0..255] as bf16 into LDS ----
    // 32 rows x 64 float4 = 2048 float4; 256 threads x 8 each, coalesced.
    #pragma unroll
    for (int it = 0; it < 8; ++it) {
        int lin = it * 256 + t;
        int row = lin >> 6;              // 0..31
        int c4  = lin & 63;              // float4 index within row
        float4 w = *reinterpret_cast<const float4*>(
            Ww + (size_t)(nb + row) * HID + (c4 << 2));
        uint2 pk;
        pk.x = ((unsigned)bf16rne(w.y) << 16) | bf16rne(w.x);
        pk.y = ((unsigned)bf16rne(w.w) << 16) | bf16rne(w.z);
        *reinterpret_cast<uint2*>(
            reinterpret_cast<char*>(Bs) + row * (LDSROW * 2) + (c4 << 3)) = pk;
    }
    __syncthreads();

    // ---- compute: 2 n-subtiles x 2 m-frags x 8 ks = 32 MFMA per wave ----
    #pragma unroll
    for (int s = 0; s < 2; ++s) {
        short8 aw[8];
        #pragma unroll
        for (int ks = 0; ks < 8; ++ks)
            aw[ks] = *reinterpret_cast<const short8*>(
                reinterpret_cast<const char*>(Bs) +
                (s * 16 + l15) * (LDSROW * 2) + lq * 16 + ks * 64);

        f32x4 acc[2] = {};
        #pragma unroll
        for (int ks = 0; ks < 8; ++ks)
            #pragma unroll
            for (int mf = 0; mf < 2; ++mf)
                acc[mf] = __builtin_amdgcn_mfma_f32_16x16x32_bf16(
                    aw[ks], bh[mf * 8 + ks], acc[mf], 0, 0, 0);

        // D[n][m]: col = l15 = m, rows = lq*4 + reg = 4 consecutive n
        int ncol = nb + s * 16 + lq * 4;
        float4 bias = *reinterpret_cast<const float4*>(b_out + ncol);
        f32x4 bv; bv[0] = bias.x; bv[1] = bias.y; bv[2] = bias.z; bv[3] = bias.w;
        #pragma unroll
        for (int mf = 0; mf < 2; ++mf) {
            f32x4 o = acc[mf] + bv;
            *reinterpret_cast<f32x4*>(
                out + (size_t)(m0 + mf * 16 + l15) * NCLS + ncol) = o;
        }
    }
}

// ---------------------------------------------------------------------------
extern "C" void kernel_launch(void* const* d_in, const int* in_sizes, int n_in,
                              void* d_out, int out_size, void* d_ws, size_t ws_size,
                              hipStream_t stream) {
    const int*   X       = (const int*)  d_in[0];
    const float* C_table = (const float*)d_in[1];
    const float* U_i     = (const float*)d_in[2];
    const float* b_i     = (const float*)d_in[4];
    const float* U_c     = (const float*)d_in[8];
    const float* b_c     = (const float*)d_in[10];
    const float* U_o     = (const float*)d_in[11];
    const float* b_o     = (const float*)d_in[13];
    const float* W_w     = (const float*)d_in[26];
    const float* b_out   = (const float*)d_in[27];
    float* out = (float*)d_out;

    unsigned short* hws = (unsigned short*)d_ws;  // bf16 h_last [256][256]

    lstm_h_last<<<B_SZ / 4, 256, 0, stream>>>(X, C_table, U_i, b_i, U_c, b_c,
                                              U_o, b_o, hws);
    logits_gemm<<<(NCLS / BN) * 2, 256, 0, stream>>>(hws, W_w, b_out, out);
}

// Round 4
// 35.127 us; speedup vs baseline: 1.7089x; 1.2604x over previous
//
#include <hip/hip_runtime.h>

#define B_SZ   256
#define T_SZ   512
#define EMB    128
#define HID    256
#define NCLS   32000

typedef __attribute__((ext_vector_type(8))) short short8;
typedef __attribute__((ext_vector_type(4))) float f32x4;

__device__ inline unsigned short bf16rne(float f) {
    union { float f; unsigned int u; } v; v.f = f;
    unsigned int u = v.u;
    u += 0x7FFFu + ((u >> 16) & 1u);   // round-to-nearest-even
    return (unsigned short)(u >> 16);
}

// ---------------------------------------------------------------------------
// Kernel 1: h_last[b][k] = o0 * tanh(i0 * g0) for the LAST timestep only.
// (layer-0 state never updates; layer-1 scan is discarded; only t = T-1 used)
// 128 blocks x 256 thr, 2 batch rows per block, unroll-8 e-loop for MLP.
// ---------------------------------------------------------------------------
__global__ __launch_bounds__(256)
void lstm_h_last(const int* __restrict__ X, const float* __restrict__ C_table,
                 const float* __restrict__ U_i, const float* __restrict__ b_i,
                 const float* __restrict__ U_c, const float* __restrict__ b_c,
                 const float* __restrict__ U_o, const float* __restrict__ b_o,
                 unsigned short* __restrict__ hws) {
    __shared__ float e[2][EMB];
    __shared__ int idx[2];
    const int t  = threadIdx.x;          // 0..255
    const int b2 = blockIdx.x * 2;

    if (t < 2) idx[t] = X[(size_t)(b2 + t) * T_SZ + (T_SZ - 1)];
    __syncthreads();
    e[t >> 7][t & 127] = C_table[(size_t)idx[t >> 7] * EMB + (t & 127)];
    __syncthreads();

    const int k = t;  // hidden index
    float ai0 = 0.f, ac0 = 0.f, ao0 = 0.f;
    float ai1 = 0.f, ac1 = 0.f, ao1 = 0.f;

    #pragma unroll 8
    for (int ee = 0; ee < EMB; ++ee) {
        float ui = U_i[ee * HID + k];
        float uc = U_c[ee * HID + k];
        float uo = U_o[ee * HID + k];
        float e0 = e[0][ee], e1 = e[1][ee];
        ai0 += e0 * ui; ac0 += e0 * uc; ao0 += e0 * uo;
        ai1 += e1 * ui; ac1 += e1 * uc; ao1 += e1 * uo;
    }

    const float bi = b_i[k], bc = b_c[k], bo = b_o[k];
    {
        float i0 = 1.f / (1.f + expf(-(ai0 + bi)));
        float g0 = tanhf(ac0 + bc);
        float o0 = 1.f / (1.f + expf(-(ao0 + bo)));
        hws[(size_t)b2 * HID + k] = bf16rne(o0 * tanhf(i0 * g0));
    }
    {
        float i0 = 1.f / (1.f + expf(-(ai1 + bi)));
        float g0 = tanhf(ac1 + bc);
        float o0 = 1.f / (1.f + expf(-(ao1 + bo)));
        hws[(size_t)(b2 + 1) * HID + k] = bf16rne(o0 * tanhf(i0 * g0));
    }
}

// ---------------------------------------------------------------------------
// Kernel 2: logits[m][n] = sum_k h[m][k] * W_w[n][k] + b_out[n]
// M=256 N=32000 K=256.
//
// 500 blocks x 256 thr (4 waves), __launch_bounds__(256,2) -> 2 blocks/CU.
// Wave owns 64 m-rows: bh[32] h-fragments (128 VGPR) loaded ONCE per block.
// Block owns 2 consecutive n-tiles (BN=32); W read from HBM exactly once.
// T3 minimum 2-phase pipeline: issue tile1 loads -> compute tile0 ->
// cvt+LDS-write tile1 -> barrier -> compute tile1. Loads stay in flight
// under the MFMA phase; HBM never drains at a barrier.
// LDS: 2 x 16.9 KB, rows padded to 264 bf16 (0 bank conflicts, measured).
// ---------------------------------------------------------------------------
#define BN      32
#define LDSROW  264   // bf16 elements per padded row (528 B)

__device__ __forceinline__ void stage_issue(const float* __restrict__ Ww,
                                            int nb, int t, float4 wf[8]) {
    #pragma unroll
    for (int it = 0; it < 8; ++it) {
        int lin = it * 256 + t;
        int row = lin >> 6;              // 0..31
        int c4  = lin & 63;              // float4 index within row
        wf[it] = *reinterpret_cast<const float4*>(
            Ww + (size_t)(nb + row) * HID + (c4 << 2));
    }
}

__device__ __forceinline__ void stage_write(unsigned short* __restrict__ Bs,
                                            int t, const float4 wf[8]) {
    #pragma unroll
    for (int it = 0; it < 8; ++it) {
        int lin = it * 256 + t;
        int row = lin >> 6;
        int c4  = lin & 63;
        uint2 pk;
        pk.x = ((unsigned)bf16rne(wf[it].y) << 16) | bf16rne(wf[it].x);
        pk.y = ((unsigned)bf16rne(wf[it].w) << 16) | bf16rne(wf[it].z);
        *reinterpret_cast<uint2*>(
            reinterpret_cast<char*>(Bs) + row * (LDSROW * 2) + (c4 << 3)) = pk;
    }
}

__device__ __forceinline__ void compute_tile(const unsigned short* __restrict__ Bs,
                                             const short8 bh[32],
                                             const float* __restrict__ b_out,
                                             float* __restrict__ out,
                                             int nb, int m0, int l15, int lq) {
    #pragma unroll
    for (int s = 0; s < 2; ++s) {
        short8 aw[8];
        #pragma unroll
        for (int ks = 0; ks < 8; ++ks)
            aw[ks] = *reinterpret_cast<const short8*>(
                reinterpret_cast<const char*>(Bs) +
                (s * 16 + l15) * (LDSROW * 2) + lq * 16 + ks * 64);

        f32x4 acc[4] = {};
        #pragma unroll
        for (int ks = 0; ks < 8; ++ks)
            #pragma unroll
            for (int mf = 0; mf < 4; ++mf)
                acc[mf] = __builtin_amdgcn_mfma_f32_16x16x32_bf16(
                    aw[ks], bh[mf * 8 + ks], acc[mf], 0, 0, 0);

        // D[n][m]: col = l15 = m, rows = lq*4 + reg = 4 consecutive n
        int ncol = nb + s * 16 + lq * 4;
        float4 bias = *reinterpret_cast<const float4*>(b_out + ncol);
        f32x4 bv; bv[0] = bias.x; bv[1] = bias.y; bv[2] = bias.z; bv[3] = bias.w;
        #pragma unroll
        for (int mf = 0; mf < 4; ++mf) {
            f32x4 o = acc[mf] + bv;
            *reinterpret_cast<f32x4*>(
                out + (size_t)(m0 + mf * 16 + l15) * NCLS + ncol) = o;
        }
    }
}

__global__ __launch_bounds__(256, 2)
void logits_gemm(const unsigned short* __restrict__ hws,
                 const float* __restrict__ Ww,
                 const float* __restrict__ b_out,
                 float* __restrict__ out) {
    __shared__ unsigned short Bs[2][BN * LDSROW];   // 2 x 16.9 KB

    const int t    = threadIdx.x;        // 0..255
    const int wid  = t >> 6;             // 0..3
    const int lane = t & 63;
    const int l15  = lane & 15;
    const int lq   = lane >> 4;          // 0..3

    const int m0  = wid * 64;            // this wave's 64-m strip
    const int nb0 = blockIdx.x * (2 * BN);
    const int nb1 = nb0 + BN;

    // ---- bh: h[m0 + mf*16 + l15][lq*8 + ks*32], once per block, in regs ----
    short8 bh[32];
    #pragma unroll
    for (int mf = 0; mf < 4; ++mf)
        #pragma unroll
        for (int ks = 0; ks < 8; ++ks)
            bh[mf * 8 + ks] = *reinterpret_cast<const short8*>(
                hws + (size_t)(m0 + mf * 16 + l15) * HID + lq * 8 + ks * 32);

    float4 wf[8];
    // prologue: stage tile0
    stage_issue(Ww, nb0, t, wf);
    stage_write(&Bs[0][0], t, wf);
    __syncthreads();

    // pipelined iteration: tile1 loads fly under tile0's compute
    stage_issue(Ww, nb1, t, wf);
    compute_tile(&Bs[0][0], bh, b_out, out, nb0, m0, l15, lq);
    stage_write(&Bs[1][0], t, wf);
    __syncthreads();

    compute_tile(&Bs[1][0], bh, b_out, out, nb1, m0, l15, lq);
}

// ---------------------------------------------------------------------------
extern "C" void kernel_launch(void* const* d_in, const int* in_sizes, int n_in,
                              void* d_out, int out_size, void* d_ws, size_t ws_size,
                              hipStream_t stream) {
    const int*   X       = (const int*)  d_in[0];
    const float* C_table = (const float*)d_in[1];
    const float* U_i     = (const float*)d_in[2];
    const float* b_i     = (const float*)d_in[4];
    const float* U_c     = (const float*)d_in[8];
    const float* b_c     = (const float*)d_in[10];
    const float* U_o     = (const float*)d_in[11];
    const float* b_o     = (const float*)d_in[13];
    const float* W_w     = (const float*)d_in[26];
    const float* b_out   = (const float*)d_in[27];
    float* out = (float*)d_out;

    unsigned short* hws = (unsigned short*)d_ws;  // bf16 h_last [256][256]

    lstm_h_last<<<B_SZ / 2, 256, 0, stream>>>(X, C_table, U_i, b_i, U_c, b_c,
                                              U_o, b_o, hws);
    logits_gemm<<<NCLS / (2 * BN), 256, 0, stream>>>(hws, W_w, b_out, out);
}